// Round 1
// baseline (1155.365 us; speedup 1.0000x reference)
//
#include <hip/hip_runtime.h>
#include <stdint.h>

#define BIGF 1e10f
#define T_LEN 1024
#define D_DIM 64
#define BATCH 32
#define L2E 1.4426950408889634f   /* log2(e) */
#define LN2F 0.6931471805599453f

#if defined(__has_builtin)
#if __has_builtin(__builtin_amdgcn_exp2f)
#define FAST_EXP2(x) __builtin_amdgcn_exp2f(x)
#endif
#if __has_builtin(__builtin_amdgcn_logf)
#define FAST_LOG2(x) __builtin_amdgcn_logf(x)
#endif
#endif
#ifndef FAST_EXP2
#define FAST_EXP2(x) exp2f(x)
#endif
#ifndef FAST_LOG2
#define FAST_LOG2(x) log2f(x)
#endif

__device__ __forceinline__ unsigned short f2bf_rne(float f) {
    unsigned int u = __float_as_uint(f);
    u += 0x7fffu + ((u >> 16) & 1u);   // round-to-nearest-even; inputs are finite
    return (unsigned short)(u >> 16);
}

// softmin(a,b,c) = m - ln(e^{m-a} + e^{m-b} + e^{m-c}),  m = min(a,b,c), gamma = 1
__device__ __forceinline__ float softmin3(float a, float b, float c) {
    float m = fminf(a, fminf(b, c));
    float s = FAST_EXP2((m - a) * L2E) + FAST_EXP2((m - b) * L2E) + FAST_EXP2((m - c) * L2E);
    return m - FAST_LOG2(s) * LN2F;   // s >= 1 always (one exponent is exactly 0)
}

// ---------------------------------------------------------------------------
// Kernel 1: cost[b][i][j] = max(0, x2_i + y2_j - 2*dot(x_i, y_j)) as bf16.
// 64x64 tile per block, 256 threads, 4x4 microtile, K = 64 (full D).
// LDS tiles stored transposed [d][i] so the K-loop uses ds_read_b128.
// ---------------------------------------------------------------------------
__global__ __launch_bounds__(256) void cost_gemm(const float* __restrict__ x,
                                                 const float* __restrict__ y,
                                                 unsigned short* __restrict__ cost) {
    __shared__ float As[D_DIM][68];   // [d][i], pad to 68 to break stride-64 banks
    __shared__ float Bs[D_DIM][68];   // [d][j]
    __shared__ float x2s[64];
    __shared__ float y2s[64];

    const int b   = blockIdx.z;
    const int i0  = blockIdx.y * 64;
    const int j0  = blockIdx.x * 64;
    const int tid = threadIdx.x;          // 0..255
    const int tx  = tid & 15;
    const int ty  = tid >> 4;

    const float4* xt = (const float4*)(x + ((size_t)b * T_LEN + i0) * D_DIM); // contiguous 16KB
    const float4* yt = (const float4*)(y + ((size_t)b * T_LEN + j0) * D_DIM);

    #pragma unroll
    for (int s = 0; s < 4; ++s) {
        int f   = tid + s * 256;          // float4 index 0..1023
        int l   = f * 4;                  // flat float index in the 64x64 tile
        int row = l >> 6;                 // tile row (i or j local)
        int d0  = l & 63;                 // dim
        float4 va = xt[f];
        float4 vb = yt[f];
        As[d0 + 0][row] = va.x; As[d0 + 1][row] = va.y;
        As[d0 + 2][row] = va.z; As[d0 + 3][row] = va.w;
        Bs[d0 + 0][row] = vb.x; Bs[d0 + 1][row] = vb.y;
        Bs[d0 + 2][row] = vb.z; Bs[d0 + 3][row] = vb.w;
    }
    __syncthreads();

    if (tid < 64) {
        float s = 0.f;
        #pragma unroll 16
        for (int d = 0; d < 64; ++d) { float v = As[d][tid]; s = fmaf(v, v, s); }
        x2s[tid] = s;
    } else if (tid < 128) {
        int t = tid - 64;
        float s = 0.f;
        #pragma unroll 16
        for (int d = 0; d < 64; ++d) { float v = Bs[d][t]; s = fmaf(v, v, s); }
        y2s[t] = s;
    }
    __syncthreads();

    float acc[4][4] = {};
    #pragma unroll 16
    for (int d = 0; d < 64; ++d) {
        float4 av = *(const float4*)&As[d][ty * 4];
        float4 bv = *(const float4*)&Bs[d][tx * 4];
        float ar[4] = {av.x, av.y, av.z, av.w};
        float br[4] = {bv.x, bv.y, bv.z, bv.w};
        #pragma unroll
        for (int r = 0; r < 4; ++r)
            #pragma unroll
            for (int c = 0; c < 4; ++c)
                acc[r][c] = fmaf(ar[r], br[c], acc[r][c]);
    }

    #pragma unroll
    for (int r = 0; r < 4; ++r) {
        float x2v = x2s[ty * 4 + r];
        float c0 = fmaxf(0.f, x2v + y2s[tx * 4 + 0] - 2.f * acc[r][0]);
        float c1 = fmaxf(0.f, x2v + y2s[tx * 4 + 1] - 2.f * acc[r][1]);
        float c2 = fmaxf(0.f, x2v + y2s[tx * 4 + 2] - 2.f * acc[r][2]);
        float c3 = fmaxf(0.f, x2v + y2s[tx * 4 + 3] - 2.f * acc[r][3]);
        ushort4 o;
        o.x = f2bf_rne(c0); o.y = f2bf_rne(c1); o.z = f2bf_rne(c2); o.w = f2bf_rne(c3);
        size_t off = ((size_t)b * T_LEN + (size_t)(i0 + ty * 4 + r)) * T_LEN + (size_t)(j0 + tx * 4);
        *(ushort4*)(cost + off) = o;
    }
}

// ---------------------------------------------------------------------------
// Kernel 2 (path A): anti-diagonal DP, one block per batch, thread = DP row.
// buf rotation d_{k-2}, d_{k-1} -> d_k, one __syncthreads per diagonal.
// Each thread streams its own bf16 cost row through a 16B register buffer
// (one aligned uint4 load per 8 diagonals).
// ---------------------------------------------------------------------------
__global__ __launch_bounds__(1024) void dp_precost(const unsigned short* __restrict__ cost,
                                                   float* __restrict__ out) {
    __shared__ float bufs[3][1026];
    const int b   = blockIdx.x;
    const int tid = threadIdx.x;          // i = tid + 1 in reference indexing

    bufs[0][tid] = (tid == 0) ? 0.0f : BIGF;   // d0
    bufs[1][tid] = BIGF;                       // d1
    if (tid == 0) { bufs[0][1024] = BIGF; bufs[1][1024] = BIGF; }
    __syncthreads();

    const unsigned short* rowp = cost + ((size_t)b * T_LEN + (size_t)tid) * T_LEN;

    float* p2  = bufs[0];   // d_{k-2}
    float* p1  = bufs[1];   // d_{k-1}
    float* cur = bufs[2];   // d_k

    uint4 cb = make_uint4(0u, 0u, 0u, 0u);

    for (int k = 2; k <= 2 * T_LEN; ++k) {
        const int col = k - tid - 2;      // 0-based column of Dxy
        float v = BIGF;
        if (col >= 0 && col < T_LEN) {
            if ((col & 7) == 0) cb = *(const uint4*)(rowp + col);  // 16B aligned
            int e = col & 7;
            unsigned int w = (e & 4) ? ((e & 2) ? cb.w : cb.z)
                                     : ((e & 2) ? cb.y : cb.x);
            unsigned int h = (e & 1) ? (w & 0xffff0000u) : (w << 16);
            float cval = __uint_as_float(h);
            float a  = p2[tid];           // d_{k-2}[i-1]
            float bb = p1[tid];           // d_{k-1}[i-1]
            float cc = p1[tid + 1];       // d_{k-1}[i]
            v = cval + softmin3(a, bb, cc);
        }
        cur[tid + 1] = v;
        if (tid == 0) cur[0] = BIGF;
        __syncthreads();
        float* t = p2; p2 = p1; p1 = cur; cur = t;
    }
    if (tid == 0) out[b] = p1[1024];      // d_{2T}[T]
}

// ---------------------------------------------------------------------------
// Kernel 2 (path B fallback, no workspace): costs computed on the fly.
// Thread holds x_i in 64 VGPRs; y read directly from global per diagonal.
// ---------------------------------------------------------------------------
__global__ __launch_bounds__(1024) void dp_onthefly(const float* __restrict__ x,
                                                    const float* __restrict__ y,
                                                    float* __restrict__ out) {
    __shared__ float bufs[3][1026];
    __shared__ float y2s[1024];
    const int b   = blockIdx.x;
    const int tid = threadIdx.x;

    const float4* xrow = (const float4*)(x + ((size_t)b * T_LEN + (size_t)tid) * D_DIM);
    const float4* yb   = (const float4*)(y + (size_t)b * T_LEN * D_DIM);

    float4 xr[16];
    float x2 = 0.f;
    #pragma unroll
    for (int q = 0; q < 16; ++q) {
        xr[q] = xrow[q];
        x2 = fmaf(xr[q].x, xr[q].x, x2);
        x2 = fmaf(xr[q].y, xr[q].y, x2);
        x2 = fmaf(xr[q].z, xr[q].z, x2);
        x2 = fmaf(xr[q].w, xr[q].w, x2);
    }
    float y2 = 0.f;
    #pragma unroll
    for (int q = 0; q < 16; ++q) {
        float4 v = yb[tid * 16 + q];
        y2 = fmaf(v.x, v.x, y2); y2 = fmaf(v.y, v.y, y2);
        y2 = fmaf(v.z, v.z, y2); y2 = fmaf(v.w, v.w, y2);
    }
    y2s[tid] = y2;

    bufs[0][tid] = (tid == 0) ? 0.0f : BIGF;
    bufs[1][tid] = BIGF;
    if (tid == 0) { bufs[0][1024] = BIGF; bufs[1][1024] = BIGF; }
    __syncthreads();

    float* p2  = bufs[0];
    float* p1  = bufs[1];
    float* cur = bufs[2];

    for (int k = 2; k <= 2 * T_LEN; ++k) {
        const int col = k - tid - 2;
        float v = BIGF;
        if (col >= 0 && col < T_LEN) {
            const float4* yr = yb + (size_t)col * 16;
            float dot = 0.f;
            #pragma unroll
            for (int q = 0; q < 16; ++q) {
                float4 w = yr[q];
                dot = fmaf(xr[q].x, w.x, dot);
                dot = fmaf(xr[q].y, w.y, dot);
                dot = fmaf(xr[q].z, w.z, dot);
                dot = fmaf(xr[q].w, w.w, dot);
            }
            float cval = fmaxf(0.f, x2 + y2s[col] - 2.f * dot);
            float a  = p2[tid];
            float bb = p1[tid];
            float cc = p1[tid + 1];
            v = cval + softmin3(a, bb, cc);
        }
        cur[tid + 1] = v;
        if (tid == 0) cur[0] = BIGF;
        __syncthreads();
        float* t = p2; p2 = p1; p1 = cur; cur = t;
    }
    if (tid == 0) out[b] = p1[1024];
}

extern "C" void kernel_launch(void* const* d_in, const int* in_sizes, int n_in,
                              void* d_out, int out_size, void* d_ws, size_t ws_size,
                              hipStream_t stream) {
    const float* x = (const float*)d_in[0];
    const float* y = (const float*)d_in[1];
    float* out = (float*)d_out;

    const size_t cost_bytes = (size_t)BATCH * T_LEN * T_LEN * sizeof(unsigned short); // 64 MiB

    if (ws_size >= cost_bytes) {
        unsigned short* cost = (unsigned short*)d_ws;
        dim3 grid(T_LEN / 64, T_LEN / 64, BATCH);   // 16 x 16 x 32
        cost_gemm<<<grid, 256, 0, stream>>>(x, y, cost);
        dp_precost<<<BATCH, 1024, 0, stream>>>(cost, out);
    } else {
        dp_onthefly<<<BATCH, 1024, 0, stream>>>(x, y, out);
    }
}